// Round 1
// baseline (799.123 us; speedup 1.0000x reference)
//
#include <hip/hip_runtime.h>

// Problem: B=16, C=128, H=W=64, N=4096, M=1024 (pooled), C/8=16, C/2=64.
// All fp32. Workspace layout (floats):
//   theta_ws [16][4096][16]  @ 0         (4 MB)
//   phi_ws   [16][1024][16]  @ 1048576   (1 MB)
//   g_ws     [16][1024][64]  @ 1310720   (4 MB)
//   o_ws     [16][4096][64]  @ 2359296   (16 MB)

#define NEG_HUGE -3.402823466e38f

// ---------------- Kernel A: theta = w_theta (16x128) @ x, stored [b][n][16]
__global__ __launch_bounds__(256) void k_theta(const float* __restrict__ x,
                                               const float* __restrict__ w,
                                               float* __restrict__ theta) {
    __shared__ float wt[128][16];  // transposed weights: wt[c][o]
    const int tid = threadIdx.x;
    for (int i = tid; i < 2048; i += 256) {
        int o = i & 15, c = i >> 4;
        wt[c][o] = w[o * 128 + c];
    }
    __syncthreads();
    const int b = blockIdx.x >> 4;
    const int n = ((blockIdx.x & 15) << 8) | tid;
    const float* xp = x + (size_t)b * 128 * 4096 + n;
    float acc[16];
#pragma unroll
    for (int o = 0; o < 16; ++o) acc[o] = 0.f;
    for (int c = 0; c < 128; ++c) {
        float xv = xp[(size_t)c * 4096];  // coalesced across lanes (adjacent n)
#pragma unroll
        for (int o = 0; o < 16; ++o) acc[o] = fmaf(wt[c][o], xv, acc[o]);
    }
    float4* tp = (float4*)(theta + ((size_t)b * 4096 + n) * 16);
#pragma unroll
    for (int i = 0; i < 4; ++i)
        tp[i] = make_float4(acc[4 * i], acc[4 * i + 1], acc[4 * i + 2], acc[4 * i + 3]);
}

// ---------------- Kernels B/C: conv at pooled positions, then max over 2x2.
// Output stored [b][m][OC], m = h2*32 + w2.
template <int OC>
__global__ __launch_bounds__(256) void k_pool(const float* __restrict__ x,
                                              const float* __restrict__ w,
                                              float* __restrict__ outp) {
    __shared__ float wt[128][OC];  // transposed
    const int tid = threadIdx.x;
    for (int i = tid; i < 128 * OC; i += 256) {
        int o = i % OC, c = i / OC;
        wt[c][o] = w[o * 128 + c];
    }
    __syncthreads();
    const int gid = blockIdx.x * 256 + tid;  // b*1024 + m
    const int b = gid >> 10, m = gid & 1023;
    const int h2 = m >> 5, w2 = m & 31;
    const float* xb = x + (size_t)b * 128 * 4096;
    float macc[OC];
#pragma unroll
    for (int o = 0; o < OC; ++o) macc[o] = NEG_HUGE;
    for (int sub = 0; sub < 4; ++sub) {
        int h = 2 * h2 + (sub >> 1), ww = 2 * w2 + (sub & 1);
        int n = h * 64 + ww;
        float t[OC];
#pragma unroll
        for (int o = 0; o < OC; ++o) t[o] = 0.f;
        for (int c = 0; c < 128; ++c) {
            float xv = xb[(size_t)c * 4096 + n];
#pragma unroll
            for (int o = 0; o < OC; ++o) t[o] = fmaf(wt[c][o], xv, t[o]);
        }
#pragma unroll
        for (int o = 0; o < OC; ++o) macc[o] = fmaxf(macc[o], t[o]);
    }
    float4* op = (float4*)(outp + ((size_t)b * 1024 + m) * OC);
#pragma unroll
    for (int i = 0; i < OC / 4; ++i)
        op[i] = make_float4(macc[4 * i], macc[4 * i + 1], macc[4 * i + 2], macc[4 * i + 3]);
}

// ---------------- Kernel D: fused attention.
// One thread owns one output row n: scores[n][m] over m=0..1023, softmax
// (no max-subtraction needed: |s| <~ 12 stat-bounded, exp fine in fp32),
// accumulate o[c] += p * g[c][m]. phi/g staged per 256-m tile in LDS;
// all inner-loop LDS reads are wave-uniform broadcasts.
__global__ __launch_bounds__(256) void k_attn(const float* __restrict__ theta,
                                              const float* __restrict__ phi,
                                              const float* __restrict__ g,
                                              float* __restrict__ o_ws) {
    __shared__ float phi_s[256][16];  // 16 KB
    __shared__ float g_s[256][64];    // 64 KB
    const int tid = threadIdx.x;
    const int b = blockIdx.x >> 4;
    const int n = ((blockIdx.x & 15) << 8) | tid;
    float th[16];
    const float4* tp4 = (const float4*)(theta + ((size_t)b * 4096 + n) * 16);
#pragma unroll
    for (int i = 0; i < 4; ++i) {
        float4 v = tp4[i];
        th[4 * i] = v.x; th[4 * i + 1] = v.y; th[4 * i + 2] = v.z; th[4 * i + 3] = v.w;
    }
    float acc[64];
#pragma unroll
    for (int c = 0; c < 64; ++c) acc[c] = 0.f;
    float sm = 0.f;
    for (int mt = 0; mt < 4; ++mt) {
        __syncthreads();  // protect previous tile before overwrite
        const float4* ps = (const float4*)(phi + ((size_t)b * 1024 + mt * 256) * 16);
        float4* pd = (float4*)&phi_s[0][0];
        for (int i = tid; i < 1024; i += 256) pd[i] = ps[i];
        const float4* gs = (const float4*)(g + ((size_t)b * 1024 + mt * 256) * 64);
        float4* gd = (float4*)&g_s[0][0];
        for (int i = tid; i < 4096; i += 256) gd[i] = gs[i];
        __syncthreads();
        for (int j = 0; j < 256; ++j) {
            const float* pr = phi_s[j];
            float s = 0.f;
#pragma unroll
            for (int k = 0; k < 16; ++k) s = fmaf(th[k], pr[k], s);
            float p = __expf(s);
            sm += p;
            const float* gr = g_s[j];
#pragma unroll
            for (int c = 0; c < 64; ++c) acc[c] = fmaf(p, gr[c], acc[c]);
        }
    }
    const float inv = 1.0f / sm;
    float4* op = (float4*)(o_ws + ((size_t)b * 4096 + n) * 64);
#pragma unroll
    for (int i = 0; i < 16; ++i)
        op[i] = make_float4(acc[4 * i] * inv, acc[4 * i + 1] * inv,
                            acc[4 * i + 2] * inv, acc[4 * i + 3] * inv);
}

// ---------------- Kernel E: out = gamma * (w_o @ o) + x
__global__ __launch_bounds__(256) void k_out(const float* __restrict__ o_ws,
                                             const float* __restrict__ w_o,
                                             const float* __restrict__ x,
                                             const float* __restrict__ gamma,
                                             float* __restrict__ out) {
    __shared__ float wo_s[128][64];  // 32 KB, same layout as w_o
    const int tid = threadIdx.x;
    for (int i = tid; i < 8192; i += 256) ((float*)wo_s)[i] = w_o[i];
    __syncthreads();
    const int b = blockIdx.x >> 4;
    const int n = ((blockIdx.x & 15) << 8) | tid;
    float ov[64];
    const float4* op4 = (const float4*)(o_ws + ((size_t)b * 4096 + n) * 64);
#pragma unroll
    for (int i = 0; i < 16; ++i) {
        float4 v = op4[i];
        ov[4 * i] = v.x; ov[4 * i + 1] = v.y; ov[4 * i + 2] = v.z; ov[4 * i + 3] = v.w;
    }
    const float gm = gamma[0];
    const float* xb = x + (size_t)b * 128 * 4096 + n;
    float* ob = out + (size_t)b * 128 * 4096 + n;
    for (int co = 0; co < 128; ++co) {
        const float* wr = wo_s[co];  // broadcast reads
        float s = 0.f;
#pragma unroll
        for (int ci = 0; ci < 64; ++ci) s = fmaf(wr[ci], ov[ci], s);
        ob[(size_t)co * 4096] = fmaf(gm, s, xb[(size_t)co * 4096]);
    }
}

extern "C" void kernel_launch(void* const* d_in, const int* in_sizes, int n_in,
                              void* d_out, int out_size, void* d_ws, size_t ws_size,
                              hipStream_t stream) {
    const float* x       = (const float*)d_in[0];
    const float* w_theta = (const float*)d_in[1];
    const float* w_phi   = (const float*)d_in[2];
    const float* w_g     = (const float*)d_in[3];
    const float* w_o     = (const float*)d_in[4];
    const float* gamma   = (const float*)d_in[5];
    float* out = (float*)d_out;
    float* ws = (float*)d_ws;

    float* theta_ws = ws;                    // 1048576 floats
    float* phi_ws   = ws + 1048576;          // 262144 floats
    float* g_ws     = phi_ws + 262144;       // 1048576 floats
    float* o_ws     = g_ws + 1048576;        // 4194304 floats

    k_theta<<<256, 256, 0, stream>>>(x, w_theta, theta_ws);
    k_pool<16><<<64, 256, 0, stream>>>(x, w_phi, phi_ws);
    k_pool<64><<<64, 256, 0, stream>>>(x, w_g, g_ws);
    k_attn<<<256, 256, 0, stream>>>(theta_ws, phi_ws, g_ws, o_ws);
    k_out<<<256, 256, 0, stream>>>(o_ws, w_o, x, gamma, out);
}

// Round 2
// 529.315 us; speedup vs baseline: 1.5097x; 1.5097x over previous
//
#include <hip/hip_runtime.h>

// Problem: B=16, C=128, H=W=64, N=4096, M=1024 (pooled), C/8=16, C/2=64.
// All fp32. Workspace layout (floats):
//   theta_ws [16][4096][16]  @ 0         (4 MB)
//   phi_ws   [16][1024][16]  @ 1048576   (1 MB)
//   g_ws     [16][1024][64]  @ 1310720   (4 MB)
//   o_ws     [16][4096][64]  @ 2359296   (16 MB)

// ---------------- Kernel 1: fused theta/phi/g convs + 2x2 maxpool for phi/g.
// Quad layout: thread 4k+sub owns sub-position sub of pooled quad k, so the
// 2x2 pool window lives in 4 adjacent lanes -> maxpool via __shfl_xor(1,2).
__global__ __launch_bounds__(256) void k_convs(const float* __restrict__ x,
                                               const float* __restrict__ w_theta,
                                               const float* __restrict__ w_phi,
                                               const float* __restrict__ w_g,
                                               float* __restrict__ theta_ws,
                                               float* __restrict__ phi_ws,
                                               float* __restrict__ g_ws) {
    __shared__ float wt[128][96];  // [c][0:16)=theta, [16:32)=phi, [32:96)=g  (48 KB)
    const int tid = threadIdx.x;
    for (int i = tid; i < 2048; i += 256) { int o = i >> 7, c = i & 127; wt[c][o]      = w_theta[i]; }
    for (int i = tid; i < 2048; i += 256) { int o = i >> 7, c = i & 127; wt[c][16 + o] = w_phi[i]; }
    for (int i = tid; i < 8192; i += 256) { int o = i >> 7, c = i & 127; wt[c][32 + o] = w_g[i]; }
    __syncthreads();

    const int gq  = blockIdx.x * 64 + (tid >> 2);   // global pooled index: b*1024 + m
    const int sub = tid & 3;
    const int b = gq >> 10, m = gq & 1023;
    const int h2 = m >> 5, w2 = m & 31;
    const int n = (2 * h2 + (sub >> 1)) * 64 + 2 * w2 + (sub & 1);  // full-res position

    const float* xp = x + (size_t)b * 128 * 4096 + n;
    float th[16], ph[16], gg[64];
#pragma unroll
    for (int o = 0; o < 16; ++o) { th[o] = 0.f; ph[o] = 0.f; }
#pragma unroll
    for (int o = 0; o < 64; ++o) gg[o] = 0.f;

    for (int c = 0; c < 128; ++c) {
        float xv = xp[(size_t)c * 4096];       // coalesced (2x128B segments per wave)
        const float* wr = wt[c];               // wave-uniform LDS broadcasts
#pragma unroll
        for (int o = 0; o < 16; ++o) th[o] = fmaf(wr[o], xv, th[o]);
#pragma unroll
        for (int o = 0; o < 16; ++o) ph[o] = fmaf(wr[16 + o], xv, ph[o]);
#pragma unroll
        for (int o = 0; o < 64; ++o) gg[o] = fmaf(wr[32 + o], xv, gg[o]);
    }

    // theta at full resolution
    float4* tp = (float4*)(theta_ws + ((size_t)b * 4096 + n) * 16);
#pragma unroll
    for (int i = 0; i < 4; ++i)
        tp[i] = make_float4(th[4 * i], th[4 * i + 1], th[4 * i + 2], th[4 * i + 3]);

    // 2x2 maxpool across the quad's 4 lanes
#pragma unroll
    for (int o = 0; o < 16; ++o) {
        ph[o] = fmaxf(ph[o], __shfl_xor(ph[o], 1));
        ph[o] = fmaxf(ph[o], __shfl_xor(ph[o], 2));
    }
#pragma unroll
    for (int o = 0; o < 64; ++o) {
        gg[o] = fmaxf(gg[o], __shfl_xor(gg[o], 1));
        gg[o] = fmaxf(gg[o], __shfl_xor(gg[o], 2));
    }
    if (sub == 0) {
        float4* pp = (float4*)(phi_ws + ((size_t)b * 1024 + m) * 16);
#pragma unroll
        for (int i = 0; i < 4; ++i)
            pp[i] = make_float4(ph[4 * i], ph[4 * i + 1], ph[4 * i + 2], ph[4 * i + 3]);
        float4* gp = (float4*)(g_ws + ((size_t)b * 1024 + m) * 64);
#pragma unroll
        for (int i = 0; i < 16; ++i)
            gp[i] = make_float4(gg[4 * i], gg[4 * i + 1], gg[4 * i + 2], gg[4 * i + 3]);
    }
}

// ---------------- Kernel 2: fused attention.
// One thread owns one output row n: scores[n][m] over m=0..1023, softmax
// (no max-subtraction: |s| stat-bounded ~12, exp fine in fp32),
// accumulate o[c] += p * g[c][m]. phi/g staged per 256-m tile in LDS;
// all inner-loop LDS reads are wave-uniform broadcasts.
__global__ __launch_bounds__(256) void k_attn(const float* __restrict__ theta,
                                              const float* __restrict__ phi,
                                              const float* __restrict__ g,
                                              float* __restrict__ o_ws) {
    __shared__ float phi_s[256][16];  // 16 KB
    __shared__ float g_s[256][64];    // 64 KB
    const int tid = threadIdx.x;
    const int b = blockIdx.x >> 4;
    const int n = ((blockIdx.x & 15) << 8) | tid;
    float th[16];
    const float4* tp4 = (const float4*)(theta + ((size_t)b * 4096 + n) * 16);
#pragma unroll
    for (int i = 0; i < 4; ++i) {
        float4 v = tp4[i];
        th[4 * i] = v.x; th[4 * i + 1] = v.y; th[4 * i + 2] = v.z; th[4 * i + 3] = v.w;
    }
    float acc[64];
#pragma unroll
    for (int c = 0; c < 64; ++c) acc[c] = 0.f;
    float sm = 0.f;
    for (int mt = 0; mt < 4; ++mt) {
        __syncthreads();  // protect previous tile before overwrite
        const float4* ps = (const float4*)(phi + ((size_t)b * 1024 + mt * 256) * 16);
        float4* pd = (float4*)&phi_s[0][0];
        for (int i = tid; i < 1024; i += 256) pd[i] = ps[i];
        const float4* gs = (const float4*)(g + ((size_t)b * 1024 + mt * 256) * 64);
        float4* gd = (float4*)&g_s[0][0];
        for (int i = tid; i < 4096; i += 256) gd[i] = gs[i];
        __syncthreads();
        for (int j = 0; j < 256; ++j) {
            const float* pr = phi_s[j];
            float s = 0.f;
#pragma unroll
            for (int k = 0; k < 16; ++k) s = fmaf(th[k], pr[k], s);
            float p = __expf(s);
            sm += p;
            const float* gr = g_s[j];
#pragma unroll
            for (int c = 0; c < 64; ++c) acc[c] = fmaf(p, gr[c], acc[c]);
        }
    }
    const float inv = 1.0f / sm;
    float4* op = (float4*)(o_ws + ((size_t)b * 4096 + n) * 64);
#pragma unroll
    for (int i = 0; i < 16; ++i)
        op[i] = make_float4(acc[4 * i] * inv, acc[4 * i + 1] * inv,
                            acc[4 * i + 2] * inv, acc[4 * i + 3] * inv);
}

// ---------------- Kernel 3: out = gamma * (w_o @ o) + x
__global__ __launch_bounds__(256) void k_out(const float* __restrict__ o_ws,
                                             const float* __restrict__ w_o,
                                             const float* __restrict__ x,
                                             const float* __restrict__ gamma,
                                             float* __restrict__ out) {
    __shared__ float wo_s[128][64];  // 32 KB, same layout as w_o
    const int tid = threadIdx.x;
    for (int i = tid; i < 8192; i += 256) ((float*)wo_s)[i] = w_o[i];
    __syncthreads();
    const int b = blockIdx.x >> 4;
    const int n = ((blockIdx.x & 15) << 8) | tid;
    float ov[64];
    const float4* op4 = (const float4*)(o_ws + ((size_t)b * 4096 + n) * 64);
#pragma unroll
    for (int i = 0; i < 16; ++i) {
        float4 v = op4[i];
        ov[4 * i] = v.x; ov[4 * i + 1] = v.y; ov[4 * i + 2] = v.z; ov[4 * i + 3] = v.w;
    }
    const float gm = gamma[0];
    const float* xb = x + (size_t)b * 128 * 4096 + n;
    float* ob = out + (size_t)b * 128 * 4096 + n;
    for (int co = 0; co < 128; ++co) {
        const float* wr = wo_s[co];  // broadcast reads
        float s = 0.f;
#pragma unroll
        for (int ci = 0; ci < 64; ++ci) s = fmaf(wr[ci], ov[ci], s);
        ob[(size_t)co * 4096] = fmaf(gm, s, xb[(size_t)co * 4096]);
    }
}

extern "C" void kernel_launch(void* const* d_in, const int* in_sizes, int n_in,
                              void* d_out, int out_size, void* d_ws, size_t ws_size,
                              hipStream_t stream) {
    const float* x       = (const float*)d_in[0];
    const float* w_theta = (const float*)d_in[1];
    const float* w_phi   = (const float*)d_in[2];
    const float* w_g     = (const float*)d_in[3];
    const float* w_o     = (const float*)d_in[4];
    const float* gamma   = (const float*)d_in[5];
    float* out = (float*)d_out;
    float* ws = (float*)d_ws;

    float* theta_ws = ws;                    // 1048576 floats
    float* phi_ws   = ws + 1048576;          // 262144 floats
    float* g_ws     = phi_ws + 262144;       // 1048576 floats
    float* o_ws     = g_ws + 1048576;        // 4194304 floats

    k_convs<<<256, 256, 0, stream>>>(x, w_theta, w_phi, w_g, theta_ws, phi_ws, g_ws);
    k_attn<<<256, 256, 0, stream>>>(theta_ws, phi_ws, g_ws, o_ws);
    k_out<<<256, 256, 0, stream>>>(o_ws, w_o, x, gamma, out);
}

// Round 3
// 171.457 us; speedup vs baseline: 4.6608x; 3.0872x over previous
//
#include <hip/hip_runtime.h>

// B=16, C=128, H=W=64, N=4096, M=1024, C/8=16, C/2=64. All inputs fp32.
// Internal tensors bf16 (as ushort bit patterns) in workspace:
//   theta_b [16][4096][16] @ ushort ofs 0         (2 MB)
//   phi_b   [16][1024][16] @ ushort ofs 1048576   (512 KB)
//   g_b     [16][64][1024] @ ushort ofs 1310720   (2 MB)  (c-major!)

typedef __attribute__((ext_vector_type(8))) short bf16x8;
typedef __attribute__((ext_vector_type(16))) float f32x16;

__device__ __forceinline__ ushort f2bf(float f) {
    uint u = __float_as_uint(f);
    u += 0x7FFFu + ((u >> 16) & 1u);   // round-to-nearest-even
    return (ushort)(u >> 16);
}
__device__ __forceinline__ uint pk2(float a, float b) {
    return (uint)f2bf(a) | ((uint)f2bf(b) << 16);
}

// ---------------- Kernel 1: fused convs + pool, bf16 outputs.
// grid 512: blocks [0,256) = theta/phi half, [256,512) = g half.
// Quad layout: thread 4k+sub owns sub-position sub of pooled quad k.
__global__ __launch_bounds__(256) void k_convs(const float* __restrict__ x,
                                               const float* __restrict__ w_theta,
                                               const float* __restrict__ w_phi,
                                               const float* __restrict__ w_g,
                                               ushort* __restrict__ theta_b,
                                               ushort* __restrict__ phi_b,
                                               ushort* __restrict__ g_b) {
    const int tid = threadIdx.x;
    const bool gpart = blockIdx.x >= 256;
    const int pb = blockIdx.x & 255;
    const int gq = pb * 64 + (tid >> 2);      // b*1024 + m
    const int sub = tid & 3;
    const int b = gq >> 10, m = gq & 1023;
    const int h2 = m >> 5, w2 = m & 31;
    const int n = (2 * h2 + (sub >> 1)) * 64 + 2 * w2 + (sub & 1);
    const float* xp = x + (size_t)b * 128 * 4096 + n;

    if (!gpart) {
        __shared__ float wt[128][32];  // [c][0:16)=theta, [16:32)=phi
        for (int i = tid; i < 2048; i += 256) { int o = i >> 7, c = i & 127; wt[c][o] = w_theta[i]; }
        for (int i = tid; i < 2048; i += 256) { int o = i >> 7, c = i & 127; wt[c][16 + o] = w_phi[i]; }
        __syncthreads();
        float th[16], ph[16];
#pragma unroll
        for (int o = 0; o < 16; ++o) { th[o] = 0.f; ph[o] = 0.f; }
        for (int c = 0; c < 128; ++c) {
            float xv = xp[(size_t)c * 4096];
            const float* wr = wt[c];
#pragma unroll
            for (int o = 0; o < 16; ++o) th[o] = fmaf(wr[o], xv, th[o]);
#pragma unroll
            for (int o = 0; o < 16; ++o) ph[o] = fmaf(wr[16 + o], xv, ph[o]);
        }
        uint4 t0, t1;
        t0.x = pk2(th[0], th[1]);  t0.y = pk2(th[2], th[3]);
        t0.z = pk2(th[4], th[5]);  t0.w = pk2(th[6], th[7]);
        t1.x = pk2(th[8], th[9]);  t1.y = pk2(th[10], th[11]);
        t1.z = pk2(th[12], th[13]); t1.w = pk2(th[14], th[15]);
        uint4* tp = (uint4*)(theta_b + ((size_t)b * 4096 + n) * 16);
        tp[0] = t0; tp[1] = t1;
#pragma unroll
        for (int o = 0; o < 16; ++o) {
            ph[o] = fmaxf(ph[o], __shfl_xor(ph[o], 1));
            ph[o] = fmaxf(ph[o], __shfl_xor(ph[o], 2));
        }
        if (sub == 0) {
            uint4 p0, p1;
            p0.x = pk2(ph[0], ph[1]);  p0.y = pk2(ph[2], ph[3]);
            p0.z = pk2(ph[4], ph[5]);  p0.w = pk2(ph[6], ph[7]);
            p1.x = pk2(ph[8], ph[9]);  p1.y = pk2(ph[10], ph[11]);
            p1.z = pk2(ph[12], ph[13]); p1.w = pk2(ph[14], ph[15]);
            uint4* pp = (uint4*)(phi_b + ((size_t)b * 1024 + m) * 16);
            pp[0] = p0; pp[1] = p1;
        }
    } else {
        __shared__ float wg[128][64];      // 32 KB
        __shared__ ushort gt[64][68];      // 8.5 KB transpose tile
        for (int i = tid; i < 8192; i += 256) { int o = i >> 7, c = i & 127; wg[c][o] = w_g[i]; }
        __syncthreads();
        float gg[64];
#pragma unroll
        for (int o = 0; o < 64; ++o) gg[o] = 0.f;
        for (int c = 0; c < 128; ++c) {
            float xv = xp[(size_t)c * 4096];
            const float* wr = wg[c];
#pragma unroll
            for (int o = 0; o < 64; ++o) gg[o] = fmaf(wr[o], xv, gg[o]);
        }
#pragma unroll
        for (int o = 0; o < 64; ++o) {
            gg[o] = fmaxf(gg[o], __shfl_xor(gg[o], 1));
            gg[o] = fmaxf(gg[o], __shfl_xor(gg[o], 2));
        }
        const int mq = tid >> 2;  // m within block tile (0..63)
        if (sub == 0) {
#pragma unroll
            for (int cc = 0; cc < 16; ++cc) gt[cc][mq] = f2bf(gg[cc]);
        } else if (sub == 1) {
#pragma unroll
            for (int cc = 0; cc < 16; ++cc) gt[16 + cc][mq] = f2bf(gg[16 + cc]);
        } else if (sub == 2) {
#pragma unroll
            for (int cc = 0; cc < 16; ++cc) gt[32 + cc][mq] = f2bf(gg[32 + cc]);
        } else {
#pragma unroll
            for (int cc = 0; cc < 16; ++cc) gt[48 + cc][mq] = f2bf(gg[48 + cc]);
        }
        __syncthreads();
        const int c = tid >> 2, q = tid & 3;
        const uint2* s = (const uint2*)&gt[c][16 * q];
        uint2 v0 = s[0], v1 = s[1], v2 = s[2], v3 = s[3];
        const int bb = pb >> 4, mb = (pb & 15) * 64;
        uint2* dst = (uint2*)(g_b + ((size_t)bb * 64 + c) * 1024 + mb + 16 * q);
        dst[0] = v0; dst[1] = v1; dst[2] = v2; dst[3] = v3;
    }
}

// ---------------- Kernel 2: fused MFMA attention + output projection + residual.
// grid 512 = 16 batches x 32 n-tiles of 128. 4 waves; wave owns 32 n-rows.
// All MFMA 32x32x16 bf16. Swapped operands throughout so lanes own col=n.
__global__ __launch_bounds__(256) void k_attn(const ushort* __restrict__ theta_b,
                                              const ushort* __restrict__ phi_b,
                                              const ushort* __restrict__ g_b,
                                              const float* __restrict__ w_o,
                                              const float* __restrict__ x,
                                              const float* __restrict__ gamma,
                                              float* __restrict__ out) {
    __shared__ ushort p_t[4][32][68];  // per-wave private P tile (stride 68 kills conflicts)
    const int tid = threadIdx.x;
    const int wave = tid >> 6, lane = tid & 63;
    const int l31 = lane & 31, h = lane >> 5;
    const int b = blockIdx.x >> 5, nt = blockIdx.x & 31;
    const int n = nt * 128 + wave * 32 + l31;  // this lane's n-column

    // theta B-frag (col=n, k=8h+j), held all kernel
    bf16x8 thf = *(const bf16x8*)(theta_b + ((size_t)b * 4096 + n) * 16 + h * 8);

    f32x16 o0 = {0,0,0,0,0,0,0,0,0,0,0,0,0,0,0,0};
    f32x16 o1 = {0,0,0,0,0,0,0,0,0,0,0,0,0,0,0,0};
    float sm = 0.f;
    ushort* prow = &p_t[wave][l31][0];

    for (int mt = 0; mt < 32; ++mt) {
        const int m0 = mt * 32;
        // phi A-frag (row=m0+l31, k=8h+j)
        bf16x8 phf = *(const bf16x8*)(phi_b + ((size_t)b * 1024 + m0 + l31) * 16 + h * 8);
        f32x16 S = {0,0,0,0,0,0,0,0,0,0,0,0,0,0,0,0};
        S = __builtin_amdgcn_mfma_f32_32x32x16_bf16(phf, thf, S, 0, 0, 0);
        // D: col=n (this lane), row=m_local=(jj&3)+8*(jj>>2)+4h
        float p[16];
#pragma unroll
        for (int jj = 0; jj < 16; ++jj) { p[jj] = __expf(S[jj]); sm += p[jj]; }
        // store P row: jj=4q..4q+3 -> m_local = 8q+4h+(0..3)
#pragma unroll
        for (int q = 0; q < 4; ++q) {
            uint2 v;
            v.x = pk2(p[4 * q], p[4 * q + 1]);
            v.y = pk2(p[4 * q + 2], p[4 * q + 3]);
            *(uint2*)(prow + 8 * q + 4 * h) = v;
        }
        // PV: o^T += g * p^T  (K=16 chunks kc=0,1)
        const ushort* gp = g_b + ((size_t)b * 64 + l31) * 1024 + m0 + 8 * h;
#pragma unroll
        for (int kc = 0; kc < 2; ++kc) {
            uint2 ua = *(const uint2*)(prow + 16 * kc + 8 * h);
            uint2 ub = *(const uint2*)(prow + 16 * kc + 8 * h + 4);
            union { bf16x8 v; uint u[4]; } P;
            P.u[0] = ua.x; P.u[1] = ua.y; P.u[2] = ub.x; P.u[3] = ub.y;
            bf16x8 ga0 = *(const bf16x8*)(gp + 16 * kc);
            bf16x8 ga1 = *(const bf16x8*)(gp + 16 * kc + 32 * 1024);
            o0 = __builtin_amdgcn_mfma_f32_32x32x16_bf16(ga0, P.v, o0, 0, 0, 0);
            o1 = __builtin_amdgcn_mfma_f32_32x32x16_bf16(ga1, P.v, o1, 0, 0, 0);
        }
    }
    sm += __shfl_xor(sm, 32);        // combine complementary m-halves
    const float inv = 1.f / sm;
#pragma unroll
    for (int jj = 0; jj < 16; ++jj) { o0[jj] *= inv; o1[jj] *= inv; }

    // Build out-proj B-frags from o^T frags: slot j of chunk kc holds ci=16kc+8h+j.
    bf16x8 Bf[4];
#pragma unroll
    for (int kc = 0; kc < 4; ++kc) {
        const f32x16& oo = (kc < 2) ? o0 : o1;
        const int base = 8 * (kc & 1);
        uint Pa0 = pk2(oo[base + 0], oo[base + 1]);
        uint Pa1 = pk2(oo[base + 2], oo[base + 3]);
        uint Pb0 = pk2(oo[base + 4], oo[base + 5]);
        uint Pb1 = pk2(oo[base + 6], oo[base + 7]);
        uint z0 = h ? Pa0 : Pb0, z1 = h ? Pa1 : Pb1;  // send what partner needs
        uint r0 = (uint)__shfl_xor((int)z0, 32);
        uint r1 = (uint)__shfl_xor((int)z1, 32);
        union { bf16x8 v; uint u[4]; } Bx;
        if (h == 0) { Bx.u[0] = Pa0; Bx.u[1] = Pa1; Bx.u[2] = r0;  Bx.u[3] = r1; }
        else        { Bx.u[0] = r0;  Bx.u[1] = r1;  Bx.u[2] = Pb0; Bx.u[3] = Pb1; }
        Bf[kc] = Bx.v;
    }

    const float gm = gamma[0];
#pragma unroll
    for (int cof = 0; cof < 4; ++cof) {
        f32x16 oc = {0,0,0,0,0,0,0,0,0,0,0,0,0,0,0,0};
#pragma unroll
        for (int kc = 0; kc < 4; ++kc) {
            const float* wp = w_o + (32 * cof + l31) * 64 + 16 * kc + 8 * h;
            float4 wa = *(const float4*)(wp);
            float4 wb = *(const float4*)(wp + 4);
            union { bf16x8 v; uint u[4]; } W;
            W.u[0] = pk2(wa.x, wa.y); W.u[1] = pk2(wa.z, wa.w);
            W.u[2] = pk2(wb.x, wb.y); W.u[3] = pk2(wb.z, wb.w);
            oc = __builtin_amdgcn_mfma_f32_32x32x16_bf16(W.v, Bf[kc], oc, 0, 0, 0);
        }
        // D: col=n, row=co_local=(jj&3)+8*(jj>>2)+4h
#pragma unroll
        for (int jj = 0; jj < 16; ++jj) {
            int co = 32 * cof + (jj & 3) + 8 * (jj >> 2) + 4 * h;
            size_t idx = ((size_t)(b * 128 + co)) * 4096 + n;
            out[idx] = fmaf(gm, oc[jj], x[idx]);
        }
    }
}

extern "C" void kernel_launch(void* const* d_in, const int* in_sizes, int n_in,
                              void* d_out, int out_size, void* d_ws, size_t ws_size,
                              hipStream_t stream) {
    const float* x       = (const float*)d_in[0];
    const float* w_theta = (const float*)d_in[1];
    const float* w_phi   = (const float*)d_in[2];
    const float* w_g     = (const float*)d_in[3];
    const float* w_o     = (const float*)d_in[4];
    const float* gamma   = (const float*)d_in[5];
    float* out = (float*)d_out;

    ushort* theta_b = (ushort*)d_ws;
    ushort* phi_b   = theta_b + 1048576;
    ushort* g_b     = phi_b + 262144;

    k_convs<<<512, 256, 0, stream>>>(x, w_theta, w_phi, w_g, theta_b, phi_b, g_b);
    k_attn<<<512, 256, 0, stream>>>(theta_b, phi_b, g_b, w_o, x, gamma, out);
}

// Round 5
// 167.926 us; speedup vs baseline: 4.7588x; 1.0210x over previous
//
#include <hip/hip_runtime.h>

// B=16, C=128, H=W=64, N=4096, M=1024, C/8=16, C/2=64. All inputs fp32.
// Internal tensors bf16 (ushort bit patterns) in workspace:
//   theta_b [16][4096][16] @ ushort ofs 0         (2 MB)   (pre-scaled by log2e)
//   phi_b   [16][1024][16] @ ushort ofs 1048576   (512 KB)
//   g_b     [16][64][1024] @ ushort ofs 1310720   (2 MB)   (c-major)

typedef __attribute__((ext_vector_type(8))) short bf16x8;
typedef __attribute__((ext_vector_type(16))) float f32x16;

#define LOG2E 1.4426950408889634f

__device__ __forceinline__ ushort f2bf(float f) {
    uint u = __float_as_uint(f);
    u += 0x7FFFu + ((u >> 16) & 1u);   // RNE
    return (ushort)(u >> 16);
}
__device__ __forceinline__ uint pk2(float a, float b) {
    return (uint)f2bf(a) | ((uint)f2bf(b) << 16);
}

// ---------------- Kernel 1: fused convs + pool, bf16 outputs.
// grid 512: blocks [0,256) = theta/phi half, [256,512) = g half.
// Quad layout: thread 4k+sub owns sub-position sub of pooled quad k.
__global__ __launch_bounds__(256) void k_convs(const float* __restrict__ x,
                                               const float* __restrict__ w_theta,
                                               const float* __restrict__ w_phi,
                                               const float* __restrict__ w_g,
                                               ushort* __restrict__ theta_b,
                                               ushort* __restrict__ phi_b,
                                               ushort* __restrict__ g_b) {
    const int tid = threadIdx.x;
    const bool gpart = blockIdx.x >= 256;
    const int pb = blockIdx.x & 255;
    const int gq = pb * 64 + (tid >> 2);      // b*1024 + m
    const int sub = tid & 3;
    const int b = gq >> 10, m = gq & 1023;
    const int h2 = m >> 5, w2 = m & 31;
    const int n = (2 * h2 + (sub >> 1)) * 64 + 2 * w2 + (sub & 1);
    const float* xp = x + (size_t)b * 128 * 4096 + n;

    if (!gpart) {
        __shared__ float wt[128][32];  // [c][0:16)=theta*log2e, [16:32)=phi
        for (int i = tid; i < 2048; i += 256) { int o = i >> 7, c = i & 127; wt[c][o] = w_theta[i] * LOG2E; }
        for (int i = tid; i < 2048; i += 256) { int o = i >> 7, c = i & 127; wt[c][16 + o] = w_phi[i]; }
        __syncthreads();
        float th[16], ph[16];
#pragma unroll
        for (int o = 0; o < 16; ++o) { th[o] = 0.f; ph[o] = 0.f; }
        for (int c = 0; c < 128; ++c) {
            float xv = xp[(size_t)c * 4096];
            const float* wr = wt[c];
#pragma unroll
            for (int o = 0; o < 16; ++o) th[o] = fmaf(wr[o], xv, th[o]);
#pragma unroll
            for (int o = 0; o < 16; ++o) ph[o] = fmaf(wr[16 + o], xv, ph[o]);
        }
        uint4 t0, t1;
        t0.x = pk2(th[0], th[1]);  t0.y = pk2(th[2], th[3]);
        t0.z = pk2(th[4], th[5]);  t0.w = pk2(th[6], th[7]);
        t1.x = pk2(th[8], th[9]);  t1.y = pk2(th[10], th[11]);
        t1.z = pk2(th[12], th[13]); t1.w = pk2(th[14], th[15]);
        uint4* tp = (uint4*)(theta_b + ((size_t)b * 4096 + n) * 16);
        tp[0] = t0; tp[1] = t1;
#pragma unroll
        for (int o = 0; o < 16; ++o) {
            ph[o] = fmaxf(ph[o], __shfl_xor(ph[o], 1));
            ph[o] = fmaxf(ph[o], __shfl_xor(ph[o], 2));
        }
        if (sub == 0) {
            uint4 p0, p1;
            p0.x = pk2(ph[0], ph[1]);  p0.y = pk2(ph[2], ph[3]);
            p0.z = pk2(ph[4], ph[5]);  p0.w = pk2(ph[6], ph[7]);
            p1.x = pk2(ph[8], ph[9]);  p1.y = pk2(ph[10], ph[11]);
            p1.z = pk2(ph[12], ph[13]); p1.w = pk2(ph[14], ph[15]);
            uint4* pp = (uint4*)(phi_b + ((size_t)b * 1024 + m) * 16);
            pp[0] = p0; pp[1] = p1;
        }
    } else {
        __shared__ float wg[128][64];      // 32 KB
        __shared__ ushort gt[64][68];      // 8.5 KB transpose tile
        for (int i = tid; i < 8192; i += 256) { int o = i >> 7, c = i & 127; wg[c][o] = w_g[i]; }
        __syncthreads();
        float gg[64];
#pragma unroll
        for (int o = 0; o < 64; ++o) gg[o] = 0.f;
        for (int c = 0; c < 128; ++c) {
            float xv = xp[(size_t)c * 4096];
            const float* wr = wg[c];
#pragma unroll
            for (int o = 0; o < 64; ++o) gg[o] = fmaf(wr[o], xv, gg[o]);
        }
#pragma unroll
        for (int o = 0; o < 64; ++o) {
            gg[o] = fmaxf(gg[o], __shfl_xor(gg[o], 1));
            gg[o] = fmaxf(gg[o], __shfl_xor(gg[o], 2));
        }
        const int mq = tid >> 2;  // m within block tile (0..63)
        if (sub == 0) {
#pragma unroll
            for (int cc = 0; cc < 16; ++cc) gt[cc][mq] = f2bf(gg[cc]);
        } else if (sub == 1) {
#pragma unroll
            for (int cc = 0; cc < 16; ++cc) gt[16 + cc][mq] = f2bf(gg[16 + cc]);
        } else if (sub == 2) {
#pragma unroll
            for (int cc = 0; cc < 16; ++cc) gt[32 + cc][mq] = f2bf(gg[32 + cc]);
        } else {
#pragma unroll
            for (int cc = 0; cc < 16; ++cc) gt[48 + cc][mq] = f2bf(gg[48 + cc]);
        }
        __syncthreads();
        const int c = tid >> 2, q = tid & 3;
        const uint2* s = (const uint2*)&gt[c][16 * q];
        uint2 v0 = s[0], v1 = s[1], v2 = s[2], v3 = s[3];
        const int bb = pb >> 4, mb = (pb & 15) * 64;
        uint2* dst = (uint2*)(g_b + ((size_t)bb * 64 + c) * 1024 + mb + 16 * q);
        dst[0] = v0; dst[1] = v1; dst[2] = v2; dst[3] = v3;
    }
}

// ---------------- Kernel 2: fused MFMA attention + out-proj + residual.
// grid 512 = 16 batches x 32 n-tiles of 128. 4 waves; wave owns 32 n-cols.
// All MFMA 32x32x16 bf16, swapped operands (lanes own col=n). P never
// touches LDS: pack pairs + __shfl_xor(32) half-exchange (same select
// pattern as the proven epilogue) assemble PV B-frags in registers.
__global__ __launch_bounds__(256) void k_attn(const ushort* __restrict__ theta_b,
                                              const ushort* __restrict__ phi_b,
                                              const ushort* __restrict__ g_b,
                                              const float* __restrict__ w_o,
                                              const float* __restrict__ x,
                                              const float* __restrict__ gamma,
                                              float* __restrict__ out) {
    const int tid = threadIdx.x;
    const int wave = tid >> 6, lane = tid & 63;
    const int l31 = lane & 31, h = lane >> 5;
    const int b = blockIdx.x >> 5, nt = blockIdx.x & 31;
    const int n = nt * 128 + wave * 32 + l31;  // this lane's n-column

    // theta B-frag (col=n, k=8h+j), held all kernel (pre-scaled by log2e)
    bf16x8 thf = *(const bf16x8*)(theta_b + ((size_t)b * 4096 + n) * 16 + h * 8);

    const ushort* pbase = phi_b + (size_t)b * 1024 * 16 + h * 8;
    const ushort* gbase = g_b + ((size_t)b * 64 + l31) * 1024 + 8 * h;

    f32x16 o0 = {0,0,0,0,0,0,0,0,0,0,0,0,0,0,0,0};
    f32x16 o1 = {0,0,0,0,0,0,0,0,0,0,0,0,0,0,0,0};
    float sm0 = 0.f, sm1 = 0.f;

    // prefetch mt=0 fragments
    bf16x8 phf = *(const bf16x8*)(pbase + (size_t)l31 * 16);
    bf16x8 gA0 = *(const bf16x8*)(gbase);
    bf16x8 gA1 = *(const bf16x8*)(gbase + 32 * 1024);
    bf16x8 gB0 = *(const bf16x8*)(gbase + 16);
    bf16x8 gB1 = *(const bf16x8*)(gbase + 16 + 32 * 1024);

    for (int mt = 0; mt < 32; ++mt) {
        // issue mt+1 prefetch first so L2 latency hides under exp/pack/MFMA
        const int m1 = ((mt + 1) & 31) * 32;
        bf16x8 nphf = *(const bf16x8*)(pbase + (size_t)(m1 + l31) * 16);
        bf16x8 ngA0 = *(const bf16x8*)(gbase + m1);
        bf16x8 ngA1 = *(const bf16x8*)(gbase + m1 + 32 * 1024);
        bf16x8 ngB0 = *(const bf16x8*)(gbase + m1 + 16);
        bf16x8 ngB1 = *(const bf16x8*)(gbase + m1 + 16 + 32 * 1024);

        f32x16 S = {0,0,0,0,0,0,0,0,0,0,0,0,0,0,0,0};
        S = __builtin_amdgcn_mfma_f32_32x32x16_bf16(phf, thf, S, 0, 0, 0);
        // lane holds S rows m_local=(jj&3)+8*(jj>>2)+4h, col n; S is log2-scaled
        float p[16];
#pragma unroll
        for (int jj = 0; jj < 16; ++jj) p[jj] = exp2f(S[jj]);
        // balanced-tree accumulate of the softmax denominator
        sm0 += ((p[0] + p[1]) + (p[2] + p[3])) + ((p[4] + p[5]) + (p[6] + p[7]));
        sm1 += ((p[8] + p[9]) + (p[10] + p[11])) + ((p[12] + p[13]) + (p[14] + p[15]));

        // pack pairs (proven manual RNE), then half-exchange via shfl_xor(32).
        // h=0 holds m {0-3,8-11,16-19,24-27}, h=1 holds m {4-7,12-15,20-23,28-31}.
        uint c0 = pk2(p[0], p[1]),   c1 = pk2(p[2], p[3]);    // h=0: m(0,1),(2,3)   h=1: m(4,5),(6,7)
        uint c2 = pk2(p[4], p[5]),   c3 = pk2(p[6], p[7]);    // h=0: m(8,9),(10,11) h=1: m(12,13),(14,15)
        uint c4 = pk2(p[8], p[9]),   c5 = pk2(p[10], p[11]);  // h=0: m(16,17),(18,19) h=1: m(20,21),(22,23)
        uint c6 = pk2(p[12], p[13]), c7 = pk2(p[14], p[15]);  // h=0: m(24,25),(26,27) h=1: m(28,29),(30,31)
        uint q0 = (uint)__shfl_xor((int)(h ? c0 : c2), 32);
        uint q1 = (uint)__shfl_xor((int)(h ? c1 : c3), 32);
        uint q2 = (uint)__shfl_xor((int)(h ? c4 : c6), 32);
        uint q3 = (uint)__shfl_xor((int)(h ? c5 : c7), 32);
        union { bf16x8 v; uint u[4]; } B0, B1;
        if (h == 0) {
            B0.u[0] = c0; B0.u[1] = c1; B0.u[2] = q0; B0.u[3] = q1;  // k=j -> m 0..7
            B1.u[0] = c4; B1.u[1] = c5; B1.u[2] = q2; B1.u[3] = q3;  // k=j -> m 16..23
        } else {
            B0.u[0] = q0; B0.u[1] = q1; B0.u[2] = c2; B0.u[3] = c3;  // k=8+j -> m 8..15
            B1.u[0] = q2; B1.u[1] = q3; B1.u[2] = c6; B1.u[3] = c7;  // k=8+j -> m 24..31
        }
        o0 = __builtin_amdgcn_mfma_f32_32x32x16_bf16(gA0, B0.v, o0, 0, 0, 0);
        o1 = __builtin_amdgcn_mfma_f32_32x32x16_bf16(gA1, B0.v, o1, 0, 0, 0);
        o0 = __builtin_amdgcn_mfma_f32_32x32x16_bf16(gB0, B1.v, o0, 0, 0, 0);
        o1 = __builtin_amdgcn_mfma_f32_32x32x16_bf16(gB1, B1.v, o1, 0, 0, 0);

        phf = nphf; gA0 = ngA0; gA1 = ngA1; gB0 = ngB0; gB1 = ngB1;
    }
    float sm = sm0 + sm1;
    sm += __shfl_xor(sm, 32);        // combine complementary m-halves
    const float inv = 1.f / sm;
#pragma unroll
    for (int jj = 0; jj < 16; ++jj) { o0[jj] *= inv; o1[jj] *= inv; }

    // Build out-proj B-frags from o^T frags: slot j of chunk kc holds ci=16kc+8h+j.
    bf16x8 Bf[4];
#pragma unroll
    for (int kc = 0; kc < 4; ++kc) {
        const f32x16& oo = (kc < 2) ? o0 : o1;
        const int base = 8 * (kc & 1);
        uint Pa0 = pk2(oo[base + 0], oo[base + 1]);
        uint Pa1 = pk2(oo[base + 2], oo[base + 3]);
        uint Pb0 = pk2(oo[base + 4], oo[base + 5]);
        uint Pb1 = pk2(oo[base + 6], oo[base + 7]);
        uint z0 = h ? Pa0 : Pb0, z1 = h ? Pa1 : Pb1;  // send what partner needs
        uint r0 = (uint)__shfl_xor((int)z0, 32);
        uint r1 = (uint)__shfl_xor((int)z1, 32);
        union { bf16x8 v; uint u[4]; } Bx;
        if (h == 0) { Bx.u[0] = Pa0; Bx.u[1] = Pa1; Bx.u[2] = r0;  Bx.u[3] = r1; }
        else        { Bx.u[0] = r0;  Bx.u[1] = r1;  Bx.u[2] = Pb0; Bx.u[3] = Pb1; }
        Bf[kc] = Bx.v;
    }

    const float gm = gamma[0];
#pragma unroll
    for (int cof = 0; cof < 4; ++cof) {
        f32x16 oc = {0,0,0,0,0,0,0,0,0,0,0,0,0,0,0,0};
#pragma unroll
        for (int kc = 0; kc < 4; ++kc) {
            const float* wp = w_o + (32 * cof + l31) * 64 + 16 * kc + 8 * h;
            float4 wa = *(const float4*)(wp);
            float4 wb = *(const float4*)(wp + 4);
            union { bf16x8 v; uint u[4]; } W;
            W.u[0] = pk2(wa.x, wa.y); W.u[1] = pk2(wa.z, wa.w);
            W.u[2] = pk2(wb.x, wb.y); W.u[3] = pk2(wb.z, wb.w);
            oc = __builtin_amdgcn_mfma_f32_32x32x16_bf16(W.v, Bf[kc], oc, 0, 0, 0);
        }
        // D: col=n, row=co_local=(jj&3)+8*(jj>>2)+4h
#pragma unroll
        for (int jj = 0; jj < 16; ++jj) {
            int co = 32 * cof + (jj & 3) + 8 * (jj >> 2) + 4 * h;
            size_t idx = ((size_t)(b * 128 + co)) * 4096 + n;
            out[idx] = fmaf(gm, oc[jj], x[idx]);
        }
    }
}

extern "C" void kernel_launch(void* const* d_in, const int* in_sizes, int n_in,
                              void* d_out, int out_size, void* d_ws, size_t ws_size,
                              hipStream_t stream) {
    const float* x       = (const float*)d_in[0];
    const float* w_theta = (const float*)d_in[1];
    const float* w_phi   = (const float*)d_in[2];
    const float* w_g     = (const float*)d_in[3];
    const float* w_o     = (const float*)d_in[4];
    const float* gamma   = (const float*)d_in[5];
    float* out = (float*)d_out;

    ushort* theta_b = (ushort*)d_ws;
    ushort* phi_b   = theta_b + 1048576;
    ushort* g_b     = phi_b + 262144;

    k_convs<<<512, 256, 0, stream>>>(x, w_theta, w_phi, w_g, theta_b, phi_b, g_b);
    k_attn<<<512, 256, 0, stream>>>(theta_b, phi_b, g_b, w_o, x, gamma, out);
}

// Round 6
// 162.454 us; speedup vs baseline: 4.9191x; 1.0337x over previous
//
#include <hip/hip_runtime.h>
#include <hip/hip_bf16.h>

// B=16, C=128, H=W=64, N=4096, M=1024, C/8=16, C/2=64. All inputs fp32.
// Internal tensors bf16 (ushort bit patterns) in workspace:
//   theta_b [16][4096][16] @ ushort ofs 0         (2 MB)   (pre-scaled by log2e)
//   phi_b   [16][1024][16] @ ushort ofs 1048576   (512 KB)
//   g_b     [16][64][1024] @ ushort ofs 1310720   (2 MB)   (c-major)

typedef __attribute__((ext_vector_type(8))) short bf16x8;
typedef __attribute__((ext_vector_type(16))) float f32x16;

#define LOG2E 1.4426950408889634f

__device__ __forceinline__ ushort f2bf(float f) {
    uint u = __float_as_uint(f);
    u += 0x7FFFu + ((u >> 16) & 1u);   // RNE
    return (ushort)(u >> 16);
}
__device__ __forceinline__ uint pk2(float a, float b) {
    return (uint)f2bf(a) | ((uint)f2bf(b) << 16);
}
// HW packed f32->bf16 (RNE, matches pk2) via official intrinsic
__device__ __forceinline__ uint pk2hw(float a, float b) {
    union { __hip_bfloat162 h; uint u; } cv;
    cv.h = __float22bfloat162_rn(make_float2(a, b));
    return cv.u;
}
// raw v_exp_f32: D = 2^S0 (scores are pre-scaled by log2e)
__device__ __forceinline__ float exp2_hw(float v) {
    float r;
    asm("v_exp_f32 %0, %1" : "=v"(r) : "v"(v));
    return r;
}

// ---------------- Kernel 1: fused convs + pool, bf16 outputs.
// grid 768: part = bid>>8: 0 = theta+phi, 1 = g channels [0,32), 2 = g [32,64).
// Quad layout: thread 4k+sub owns sub-position sub of pooled quad k.
// Single 20.5 KB LDS arena reinterpreted per part (no co-allocation).
__global__ __launch_bounds__(256) void k_convs(const float* __restrict__ x,
                                               const float* __restrict__ w_theta,
                                               const float* __restrict__ w_phi,
                                               const float* __restrict__ w_g,
                                               ushort* __restrict__ theta_b,
                                               ushort* __restrict__ phi_b,
                                               ushort* __restrict__ g_b) {
    __shared__ __align__(16) char smem[16384 + 32 * 72 * 2];  // 20992 B
    const int tid = threadIdx.x;
    const int part = blockIdx.x >> 8;
    const int pb = blockIdx.x & 255;
    const int gq = pb * 64 + (tid >> 2);      // b*1024 + m
    const int sub = tid & 3;
    const int b = gq >> 10, m = gq & 1023;
    const int h2 = m >> 5, w2 = m & 31;
    const int n = (2 * h2 + (sub >> 1)) * 64 + 2 * w2 + (sub & 1);
    const float* xp = x + (size_t)b * 128 * 4096 + n;

    if (part == 0) {
        float (*wt)[32] = (float (*)[32])smem;  // [c][0:16)=theta*log2e, [16:32)=phi
        for (int i = tid; i < 2048; i += 256) { int o = i >> 7, c = i & 127; wt[c][o] = w_theta[i] * LOG2E; }
        for (int i = tid; i < 2048; i += 256) { int o = i >> 7, c = i & 127; wt[c][16 + o] = w_phi[i]; }
        __syncthreads();
        float th[16], ph[16];
#pragma unroll
        for (int o = 0; o < 16; ++o) { th[o] = 0.f; ph[o] = 0.f; }
        for (int c = 0; c < 128; ++c) {
            float xv = xp[(size_t)c * 4096];
            const float* wr = wt[c];
#pragma unroll
            for (int o = 0; o < 16; ++o) th[o] = fmaf(wr[o], xv, th[o]);
#pragma unroll
            for (int o = 0; o < 16; ++o) ph[o] = fmaf(wr[16 + o], xv, ph[o]);
        }
        uint4 t0, t1;
        t0.x = pk2(th[0], th[1]);  t0.y = pk2(th[2], th[3]);
        t0.z = pk2(th[4], th[5]);  t0.w = pk2(th[6], th[7]);
        t1.x = pk2(th[8], th[9]);  t1.y = pk2(th[10], th[11]);
        t1.z = pk2(th[12], th[13]); t1.w = pk2(th[14], th[15]);
        uint4* tp = (uint4*)(theta_b + ((size_t)b * 4096 + n) * 16);
        tp[0] = t0; tp[1] = t1;
#pragma unroll
        for (int o = 0; o < 16; ++o) {
            ph[o] = fmaxf(ph[o], __shfl_xor(ph[o], 1));
            ph[o] = fmaxf(ph[o], __shfl_xor(ph[o], 2));
        }
        if (sub == 0) {
            uint4 p0, p1;
            p0.x = pk2(ph[0], ph[1]);  p0.y = pk2(ph[2], ph[3]);
            p0.z = pk2(ph[4], ph[5]);  p0.w = pk2(ph[6], ph[7]);
            p1.x = pk2(ph[8], ph[9]);  p1.y = pk2(ph[10], ph[11]);
            p1.z = pk2(ph[12], ph[13]); p1.w = pk2(ph[14], ph[15]);
            uint4* pp = (uint4*)(phi_b + ((size_t)b * 1024 + m) * 16);
            pp[0] = p0; pp[1] = p1;
        }
    } else {
        const int gp = part - 1;               // c-half: channels [32gp, 32gp+32)
        float (*wg)[32] = (float (*)[32])smem;
        ushort (*gt)[72] = (ushort (*)[72])(smem + 16384);  // stride 72: uint4-aligned rows
        for (int i = tid; i < 4096; i += 256) { int o = i >> 7, c = i & 127; wg[c][o] = w_g[(gp * 32 + o) * 128 + c]; }
        __syncthreads();
        float gg[32];
#pragma unroll
        for (int o = 0; o < 32; ++o) gg[o] = 0.f;
        for (int c = 0; c < 128; ++c) {
            float xv = xp[(size_t)c * 4096];
            const float* wr = wg[c];
#pragma unroll
            for (int o = 0; o < 32; ++o) gg[o] = fmaf(wr[o], xv, gg[o]);
        }
#pragma unroll
        for (int o = 0; o < 32; ++o) {
            gg[o] = fmaxf(gg[o], __shfl_xor(gg[o], 1));
            gg[o] = fmaxf(gg[o], __shfl_xor(gg[o], 2));
        }
        // transpose: all 64 lanes write (no divergence); lane (col,sub) owns rows 8sub..8sub+7
        const int col = tid >> 2;              // pooled m within block tile (0..63)
#pragma unroll
        for (int cc = 0; cc < 8; ++cc) gt[8 * sub + cc][col] = f2bf(gg[8 * sub + cc]);
        __syncthreads();
        const int cl = tid >> 3, q = tid & 7;  // row 0..31, col-chunk 0..7
        uint4 v = *(const uint4*)&gt[cl][8 * q];
        const int bb = pb >> 4, mb = (pb & 15) * 64;
        *(uint4*)(g_b + ((size_t)bb * 64 + gp * 32 + cl) * 1024 + mb + 8 * q) = v;
    }
}

// ---------------- Kernel 2: fused MFMA attention + out-proj + residual.
// grid 512 = 16 batches x 32 n-tiles of 128. 4 waves; wave owns 32 n-cols.
// All MFMA 32x32x16 bf16, swapped operands (lanes own col=n). P never
// touches LDS: HW cvt_pk pairs + __shfl_xor(32) half-exchange build B-frags.
__global__ __launch_bounds__(256) void k_attn(const ushort* __restrict__ theta_b,
                                              const ushort* __restrict__ phi_b,
                                              const ushort* __restrict__ g_b,
                                              const float* __restrict__ w_o,
                                              const float* __restrict__ x,
                                              const float* __restrict__ gamma,
                                              float* __restrict__ out) {
    const int tid = threadIdx.x;
    const int wave = tid >> 6, lane = tid & 63;
    const int l31 = lane & 31, h = lane >> 5;
    const int b = blockIdx.x >> 5, nt = blockIdx.x & 31;
    const int n = nt * 128 + wave * 32 + l31;  // this lane's n-column

    // theta B-frag (col=n, k=8h+j), held all kernel (pre-scaled by log2e)
    bf16x8 thf = *(const bf16x8*)(theta_b + ((size_t)b * 4096 + n) * 16 + h * 8);

    const ushort* pbase = phi_b + (size_t)b * 1024 * 16 + h * 8;
    const ushort* gbase = g_b + ((size_t)b * 64 + l31) * 1024 + 8 * h;

    f32x16 o0 = {0,0,0,0,0,0,0,0,0,0,0,0,0,0,0,0};
    f32x16 o1 = {0,0,0,0,0,0,0,0,0,0,0,0,0,0,0,0};
    float sm0 = 0.f, sm1 = 0.f;

    // prefetch mt=0 fragments
    bf16x8 phf = *(const bf16x8*)(pbase + (size_t)l31 * 16);
    bf16x8 gA0 = *(const bf16x8*)(gbase);
    bf16x8 gA1 = *(const bf16x8*)(gbase + 32 * 1024);
    bf16x8 gB0 = *(const bf16x8*)(gbase + 16);
    bf16x8 gB1 = *(const bf16x8*)(gbase + 16 + 32 * 1024);

    for (int mt = 0; mt < 32; ++mt) {
        // issue mt+1 prefetch first so L2 latency hides under exp/pack/MFMA
        const int m1 = ((mt + 1) & 31) * 32;
        bf16x8 nphf = *(const bf16x8*)(pbase + (size_t)(m1 + l31) * 16);
        bf16x8 ngA0 = *(const bf16x8*)(gbase + m1);
        bf16x8 ngA1 = *(const bf16x8*)(gbase + m1 + 32 * 1024);
        bf16x8 ngB0 = *(const bf16x8*)(gbase + m1 + 16);
        bf16x8 ngB1 = *(const bf16x8*)(gbase + m1 + 16 + 32 * 1024);

        f32x16 S = {0,0,0,0,0,0,0,0,0,0,0,0,0,0,0,0};
        S = __builtin_amdgcn_mfma_f32_32x32x16_bf16(phf, thf, S, 0, 0, 0);
        // lane holds S rows m_local=(jj&3)+8*(jj>>2)+4h, col n; S is log2-scaled
        float p[16];
#pragma unroll
        for (int jj = 0; jj < 16; ++jj) p[jj] = exp2_hw(S[jj]);
        // balanced-tree accumulate of the softmax denominator
        sm0 += ((p[0] + p[1]) + (p[2] + p[3])) + ((p[4] + p[5]) + (p[6] + p[7]));
        sm1 += ((p[8] + p[9]) + (p[10] + p[11])) + ((p[12] + p[13]) + (p[14] + p[15]));

        // pack pairs (HW cvt_pk, RNE), then half-exchange via shfl_xor(32).
        // h=0 holds m {0-3,8-11,16-19,24-27}, h=1 holds m {4-7,12-15,20-23,28-31}.
        uint c0 = pk2hw(p[0], p[1]),   c1 = pk2hw(p[2], p[3]);
        uint c2 = pk2hw(p[4], p[5]),   c3 = pk2hw(p[6], p[7]);
        uint c4 = pk2hw(p[8], p[9]),   c5 = pk2hw(p[10], p[11]);
        uint c6 = pk2hw(p[12], p[13]), c7 = pk2hw(p[14], p[15]);
        uint q0 = (uint)__shfl_xor((int)(h ? c0 : c2), 32);
        uint q1 = (uint)__shfl_xor((int)(h ? c1 : c3), 32);
        uint q2 = (uint)__shfl_xor((int)(h ? c4 : c6), 32);
        uint q3 = (uint)__shfl_xor((int)(h ? c5 : c7), 32);
        union { bf16x8 v; uint u[4]; } B0, B1;
        if (h == 0) {
            B0.u[0] = c0; B0.u[1] = c1; B0.u[2] = q0; B0.u[3] = q1;  // k=j -> m 0..7
            B1.u[0] = c4; B1.u[1] = c5; B1.u[2] = q2; B1.u[3] = q3;  // k=j -> m 16..23
        } else {
            B0.u[0] = q0; B0.u[1] = q1; B0.u[2] = c2; B0.u[3] = c3;  // k=8+j -> m 8..15
            B1.u[0] = q2; B1.u[1] = q3; B1.u[2] = c6; B1.u[3] = c7;  // k=8+j -> m 24..31
        }
        o0 = __builtin_amdgcn_mfma_f32_32x32x16_bf16(gA0, B0.v, o0, 0, 0, 0);
        o1 = __builtin_amdgcn_mfma_f32_32x32x16_bf16(gA1, B0.v, o1, 0, 0, 0);
        o0 = __builtin_amdgcn_mfma_f32_32x32x16_bf16(gB0, B1.v, o0, 0, 0, 0);
        o1 = __builtin_amdgcn_mfma_f32_32x32x16_bf16(gB1, B1.v, o1, 0, 0, 0);

        phf = nphf; gA0 = ngA0; gA1 = ngA1; gB0 = ngB0; gB1 = ngB1;
    }
    float sm = sm0 + sm1;
    sm += __shfl_xor(sm, 32);        // combine complementary m-halves
    const float inv = 1.f / sm;
#pragma unroll
    for (int jj = 0; jj < 16; ++jj) { o0[jj] *= inv; o1[jj] *= inv; }

    // Build out-proj B-frags from o^T frags: slot j of chunk kc holds ci=16kc+8h+j.
    bf16x8 Bf[4];
#pragma unroll
    for (int kc = 0; kc < 4; ++kc) {
        const f32x16& oo = (kc < 2) ? o0 : o1;
        const int base = 8 * (kc & 1);
        uint Pa0 = pk2(oo[base + 0], oo[base + 1]);
        uint Pa1 = pk2(oo[base + 2], oo[base + 3]);
        uint Pb0 = pk2(oo[base + 4], oo[base + 5]);
        uint Pb1 = pk2(oo[base + 6], oo[base + 7]);
        uint z0 = h ? Pa0 : Pb0, z1 = h ? Pa1 : Pb1;  // send what partner needs
        uint r0 = (uint)__shfl_xor((int)z0, 32);
        uint r1 = (uint)__shfl_xor((int)z1, 32);
        union { bf16x8 v; uint u[4]; } Bx;
        if (h == 0) { Bx.u[0] = Pa0; Bx.u[1] = Pa1; Bx.u[2] = r0;  Bx.u[3] = r1; }
        else        { Bx.u[0] = r0;  Bx.u[1] = r1;  Bx.u[2] = Pb0; Bx.u[3] = Pb1; }
        Bf[kc] = Bx.v;
    }

    const float gm = gamma[0];
#pragma unroll
    for (int cof = 0; cof < 4; ++cof) {
        f32x16 oc = {0,0,0,0,0,0,0,0,0,0,0,0,0,0,0,0};
#pragma unroll
        for (int kc = 0; kc < 4; ++kc) {
            const float* wp = w_o + (32 * cof + l31) * 64 + 16 * kc + 8 * h;
            float4 wa = *(const float4*)(wp);
            float4 wb = *(const float4*)(wp + 4);
            union { bf16x8 v; uint u[4]; } W;
            W.u[0] = pk2(wa.x, wa.y); W.u[1] = pk2(wa.z, wa.w);
            W.u[2] = pk2(wb.x, wb.y); W.u[3] = pk2(wb.z, wb.w);
            oc = __builtin_amdgcn_mfma_f32_32x32x16_bf16(W.v, Bf[kc], oc, 0, 0, 0);
        }
        // D: col=n, row=co_local=(jj&3)+8*(jj>>2)+4h
#pragma unroll
        for (int jj = 0; jj < 16; ++jj) {
            int co = 32 * cof + (jj & 3) + 8 * (jj >> 2) + 4 * h;
            size_t idx = ((size_t)(b * 128 + co)) * 4096 + n;
            out[idx] = fmaf(gm, oc[jj], x[idx]);
        }
    }
}

extern "C" void kernel_launch(void* const* d_in, const int* in_sizes, int n_in,
                              void* d_out, int out_size, void* d_ws, size_t ws_size,
                              hipStream_t stream) {
    const float* x       = (const float*)d_in[0];
    const float* w_theta = (const float*)d_in[1];
    const float* w_phi   = (const float*)d_in[2];
    const float* w_g     = (const float*)d_in[3];
    const float* w_o     = (const float*)d_in[4];
    const float* gamma   = (const float*)d_in[5];
    float* out = (float*)d_out;

    ushort* theta_b = (ushort*)d_ws;
    ushort* phi_b   = theta_b + 1048576;
    ushort* g_b     = phi_b + 262144;

    k_convs<<<768, 256, 0, stream>>>(x, w_theta, w_phi, w_g, theta_b, phi_b, g_b);
    k_attn<<<512, 256, 0, stream>>>(theta_b, phi_b, g_b, w_o, x, gamma, out);
}

// Round 9
// 146.113 us; speedup vs baseline: 5.4692x; 1.1118x over previous
//
#include <hip/hip_runtime.h>
#include <hip/hip_bf16.h>

// B=16, C=128, H=W=64, N=4096, M=1024, C/8=16, C/2=64. All inputs fp32.
// Internal tensors bf16 (ushort bit patterns) in workspace:
//   theta_b [16][4096][16] @ ushort ofs 0         (2 MB)   (pre-scaled by log2e)
//   phi_b   [16][1024][16] @ ushort ofs 1048576   (512 KB)
//   g_b     [16][64][1024] @ ushort ofs 1310720   (2 MB)   (c-major)

typedef __attribute__((ext_vector_type(8))) short bf16x8;
typedef __attribute__((ext_vector_type(16))) float f32x16;

#define LOG2E 1.4426950408889634f

__device__ __forceinline__ ushort f2bf(float f) {
    uint u = __float_as_uint(f);
    u += 0x7FFFu + ((u >> 16) & 1u);   // RNE
    return (ushort)(u >> 16);
}
__device__ __forceinline__ uint pk2(float a, float b) {
    return (uint)f2bf(a) | ((uint)f2bf(b) << 16);
}
// HW packed f32->bf16 (RNE, matches pk2)
__device__ __forceinline__ uint pk2hw(float a, float b) {
    union { __hip_bfloat162 h; uint u; } cv;
    cv.h = __float22bfloat162_rn(make_float2(a, b));
    return cv.u;
}
// raw v_exp_f32: D = 2^S0 (scores are pre-scaled by log2e)
__device__ __forceinline__ float exp2_hw(float v) {
    float r;
    asm("v_exp_f32 %0, %1" : "=v"(r) : "v"(v));
    return r;
}

// ---------------- Kernel 1: MFMA conv (theta/phi/g) + 2x2 maxpool.
// Block = 4 waves, owns one (b, h2-row): pixels p0..p0+128 (rows 2h2,2h2+1).
// x staged bf16-paired into XOR-swizzled LDS; weights pre-packed into LDS in
// MFMA A-frag order. Per wave: 32 quad-ordered columns, 8 K-chunks x 3 MFMA.
__global__ __launch_bounds__(256) void k_convs(const float* __restrict__ x,
                                               const float* __restrict__ w_theta,
                                               const float* __restrict__ w_phi,
                                               const float* __restrict__ w_g,
                                               ushort* __restrict__ theta_b,
                                               ushort* __restrict__ phi_b,
                                               ushort* __restrict__ g_b) {
    __shared__ uint  xl[8192];        // 32 KB: [pix][c-pair] bf16 pairs, swizzled
    __shared__ uint4 wl[1536];        // 24 KB: w frags [set][kc][lane]
    const int tid = threadIdx.x;
    const int b = blockIdx.x >> 5, h2 = blockIdx.x & 31;
    const int p0 = h2 * 128;

    // ---- stage x: thread = (c-pair cp = tid&63, pix-group pg = tid>>6)
    {
        const int cp = tid & 63, pg = tid >> 6;
        const float* r0 = x + ((size_t)(b * 128 + 2 * cp)) * 4096 + p0 + pg * 32;
        const float4* v0 = (const float4*)r0;
        const float4* v1 = (const float4*)(r0 + 4096);
#pragma unroll
        for (int j = 0; j < 8; ++j) {
            float4 a = v0[j], c = v1[j];
            const float* af = (const float*)&a;
            const float* cf = (const float*)&c;
#pragma unroll
            for (int e = 0; e < 4; ++e) {
                int pix = pg * 32 + 4 * j + e;
                uint u = pk2hw(af[e], cf[e]);            // (c=2cp, c=2cp+1)
                int byt = (pix * 256 + cp * 4) ^ ((pix & 15) << 4);
                xl[byt >> 2] = u;
            }
        }
    }
    // ---- stage w frags: fi = (set*8+kc)*64 + lane; 6 per thread
#pragma unroll
    for (int i = 0; i < 6; ++i) {
        int fi = tid + 256 * i;
        int ln = fi & 63, sk = fi >> 6;          // sk = set*8+kc
        int s = sk >> 3, kc = sk & 7;
        int r31 = ln & 31, rh = ln >> 5;
        int c0 = kc * 16 + rh * 8;
        const float* wr;
        float scale = 1.0f;
        if (s == 0) {
            if (r31 < 16) { wr = w_theta + r31 * 128 + c0; scale = LOG2E; }
            else          { wr = w_phi + (r31 - 16) * 128 + c0; }
        } else if (s == 1) { wr = w_g + r31 * 128 + c0; }
        else               { wr = w_g + (r31 + 32) * 128 + c0; }
        float4 wa = *(const float4*)wr, wb = *(const float4*)(wr + 4);
        uint4 fr;
        fr.x = pk2hw(wa.x * scale, wa.y * scale);
        fr.y = pk2hw(wa.z * scale, wa.w * scale);
        fr.z = pk2hw(wb.x * scale, wb.y * scale);
        fr.w = pk2hw(wb.z * scale, wb.w * scale);
        wl[fi] = fr;
    }
    __syncthreads();

    // ---- MFMA K-loop
    const int lane = tid & 63, wv = tid >> 6;
    const int l31 = lane & 31, hh = lane >> 5;
    const int sub = l31 & 3, q = wv * 8 + (l31 >> 2);           // quad in block
    const int pix = 64 * (sub >> 1) + 2 * q + (sub & 1);        // col -> pixel
    f32x16 a0 = {0,0,0,0,0,0,0,0,0,0,0,0,0,0,0,0};             // theta+phi (32 oc)
    f32x16 a1 = {0,0,0,0,0,0,0,0,0,0,0,0,0,0,0,0};             // g oc 0..31
    f32x16 a2 = {0,0,0,0,0,0,0,0,0,0,0,0,0,0,0,0};             // g oc 32..63
#pragma unroll
    for (int kc = 0; kc < 8; ++kc) {
        int byt = (pix * 256 + 32 * kc + 16 * hh) ^ ((pix & 15) << 4);
        bf16x8 xf = *(const bf16x8*)((const char*)xl + byt);
        bf16x8 w0 = *(const bf16x8*)&wl[(0 * 8 + kc) * 64 + lane];
        bf16x8 w1 = *(const bf16x8*)&wl[(1 * 8 + kc) * 64 + lane];
        bf16x8 w2 = *(const bf16x8*)&wl[(2 * 8 + kc) * 64 + lane];
        a0 = __builtin_amdgcn_mfma_f32_32x32x16_bf16(w0, xf, a0, 0, 0, 0);
        a1 = __builtin_amdgcn_mfma_f32_32x32x16_bf16(w1, xf, a1, 0, 0, 0);
        a2 = __builtin_amdgcn_mfma_f32_32x32x16_bf16(w2, xf, a2, 0, 0, 0);
    }

    // ---- epilogue. D rows: oc = (jj&3) + 8*(jj>>2) + 4*hh.
    // theta = a0 rows<16 (jj 0..7); store full-res.
    {
        const int n = h2 * 128 + pix;
        ushort* tp = theta_b + ((size_t)b * 4096 + n) * 16;
        uint2 t0, t1;
        t0.x = pk2hw(a0[0], a0[1]); t0.y = pk2hw(a0[2], a0[3]);
        t1.x = pk2hw(a0[4], a0[5]); t1.y = pk2hw(a0[6], a0[7]);
        *(uint2*)(tp + 4 * hh) = t0;
        *(uint2*)(tp + 8 + 4 * hh) = t1;
    }
    // phi = a0 rows>=16 (jj 8..15); g = a1, a2. Maxpool across subs (lanes ^1,^2).
    float ph[8], g0[16], g1[16];
#pragma unroll
    for (int jj = 0; jj < 8; ++jj) ph[jj] = a0[8 + jj];
#pragma unroll
    for (int jj = 0; jj < 16; ++jj) { g0[jj] = a1[jj]; g1[jj] = a2[jj]; }
#pragma unroll
    for (int jj = 0; jj < 8; ++jj) {
        ph[jj] = fmaxf(ph[jj], __shfl_xor(ph[jj], 1));
        ph[jj] = fmaxf(ph[jj], __shfl_xor(ph[jj], 2));
    }
#pragma unroll
    for (int jj = 0; jj < 16; ++jj) {
        g0[jj] = fmaxf(g0[jj], __shfl_xor(g0[jj], 1));
        g0[jj] = fmaxf(g0[jj], __shfl_xor(g0[jj], 2));
        g1[jj] = fmaxf(g1[jj], __shfl_xor(g1[jj], 1));
        g1[jj] = fmaxf(g1[jj], __shfl_xor(g1[jj], 2));
    }
    if (sub == 0) {
        const int m = h2 * 32 + q;
        ushort* pp = phi_b + ((size_t)b * 1024 + m) * 16;
        uint2 p0v, p1v;
        p0v.x = pk2hw(ph[0], ph[1]); p0v.y = pk2hw(ph[2], ph[3]);
        p1v.x = pk2hw(ph[4], ph[5]); p1v.y = pk2hw(ph[6], ph[7]);
        *(uint2*)(pp + 4 * hh) = p0v;
        *(uint2*)(pp + 8 + 4 * hh) = p1v;
        ushort* gp = g_b + (size_t)b * 64 * 1024 + m;
#pragma unroll
        for (int jj = 0; jj < 16; ++jj) {
            int oc = (jj & 3) + 8 * (jj >> 2) + 4 * hh;
            gp[(size_t)oc * 1024] = f2bf(g0[jj]);
            gp[(size_t)(oc + 32) * 1024] = f2bf(g1[jj]);
        }
    }
}

// ---------------- Kernel 2: fused MFMA attention + out-proj + residual.
// grid 512 = 16 batches x 32 n-tiles of 128. 4 waves; wave owns 32 n-cols.
// phi/g fragments are identical for all waves/blocks of a batch -> staged
// once per block into LDS in frag order (lane*16B), double-buffered in
// groups of 4 mt with T14 split (load group-early, ds_write group-late).
__global__ __launch_bounds__(256) void k_attn(const ushort* __restrict__ theta_b,
                                              const ushort* __restrict__ phi_b,
                                              const ushort* __restrict__ g_b,
                                              const float* __restrict__ w_o,
                                              const float* __restrict__ x,
                                              const float* __restrict__ gamma,
                                              float* __restrict__ out) {
    __shared__ uint4 sbuf[2][20][64];  // 40 KB: [buf][mtL*5+frag][lane]
    const int tid = threadIdx.x;
    const int wave = tid >> 6, lane = tid & 63;
    const int l31 = lane & 31, h = lane >> 5;
    const int b = blockIdx.x >> 5, nt = blockIdx.x & 31;
    const int n = nt * 128 + wave * 32 + l31;  // this lane's n-column

    // theta B-frag (col=n, k=8h+j), held all kernel (pre-scaled by log2e)
    bf16x8 thf = *(const bf16x8*)(theta_b + ((size_t)b * 4096 + n) * 16 + h * 8);

    // this thread's 5 staging slots: slot index = (tid>>6)+4i -> (mtL, frag)
    const ushort* sp[5];
    int sstep[5];
#pragma unroll
    for (int i = 0; i < 5; ++i) {
        int mtLf = (tid >> 6) + 4 * i;       // 0..19
        int mtL = mtLf / 5, f = mtLf % 5;
        int m0 = mtL * 32;
        if (f == 0) {
            sp[i] = phi_b + ((size_t)b * 1024 + m0 + l31) * 16 + 8 * h;
            sstep[i] = 128 * 16;
        } else {
            int off = (f >= 3 ? 16 : 0) + ((f == 2 || f == 4) ? 32 * 1024 : 0);
            sp[i] = g_b + ((size_t)b * 64 + l31) * 1024 + m0 + 8 * h + off;
            sstep[i] = 128;
        }
    }

    uint4 stg[5];
    // prologue: stage group 0
#pragma unroll
    for (int i = 0; i < 5; ++i) { stg[i] = *(const uint4*)sp[i]; sp[i] += sstep[i]; }
#pragma unroll
    for (int i = 0; i < 5; ++i) sbuf[0][(tid >> 6) + 4 * i][lane] = stg[i];
    __syncthreads();

    f32x16 o0 = {0,0,0,0,0,0,0,0,0,0,0,0,0,0,0,0};
    f32x16 o1 = {0,0,0,0,0,0,0,0,0,0,0,0,0,0,0,0};
    float sm0 = 0.f, sm1 = 0.f;

    for (int grp = 0; grp < 8; ++grp) {
        const int cur = grp & 1;
        if (grp < 7) {  // T14: issue next group's loads before compute
#pragma unroll
            for (int i = 0; i < 5; ++i) { stg[i] = *(const uint4*)sp[i]; sp[i] += sstep[i]; }
        }
#pragma unroll
        for (int mtL = 0; mtL < 4; ++mtL) {
            const uint4* fr = &sbuf[cur][mtL * 5][0];
            bf16x8 phf = *(const bf16x8*)&fr[0 * 64 + lane];
            bf16x8 gA0 = *(const bf16x8*)&fr[1 * 64 + lane];
            bf16x8 gA1 = *(const bf16x8*)&fr[2 * 64 + lane];
            bf16x8 gB0 = *(const bf16x8*)&fr[3 * 64 + lane];
            bf16x8 gB1 = *(const bf16x8*)&fr[4 * 64 + lane];

            f32x16 S = {0,0,0,0,0,0,0,0,0,0,0,0,0,0,0,0};
            S = __builtin_amdgcn_mfma_f32_32x32x16_bf16(phf, thf, S, 0, 0, 0);
            float p[16];
#pragma unroll
            for (int jj = 0; jj < 16; ++jj) p[jj] = exp2_hw(S[jj]);
            sm0 += ((p[0] + p[1]) + (p[2] + p[3])) + ((p[4] + p[5]) + (p[6] + p[7]));
            sm1 += ((p[8] + p[9]) + (p[10] + p[11])) + ((p[12] + p[13]) + (p[14] + p[15]));

            uint c0 = pk2hw(p[0], p[1]),   c1 = pk2hw(p[2], p[3]);
            uint c2 = pk2hw(p[4], p[5]),   c3 = pk2hw(p[6], p[7]);
            uint c4 = pk2hw(p[8], p[9]),   c5 = pk2hw(p[10], p[11]);
            uint c6 = pk2hw(p[12], p[13]), c7 = pk2hw(p[14], p[15]);
            uint q0 = (uint)__shfl_xor((int)(h ? c0 : c2), 32);
            uint q1 = (uint)__shfl_xor((int)(h ? c1 : c3), 32);
            uint q2 = (uint)__shfl_xor((int)(h ? c4 : c6), 32);
            uint q3 = (uint)__shfl_xor((int)(h ? c5 : c7), 32);
            union { bf16x8 v; uint u[4]; } B0, B1;
            if (h == 0) {
                B0.u[0] = c0; B0.u[1] = c1; B0.u[2] = q0; B0.u[3] = q1;
                B1.u[0] = c4; B1.u[1] = c5; B1.u[2] = q2; B1.u[3] = q3;
            } else {
                B0.u[0] = q0; B0.u[1] = q1; B0.u[2] = c2; B0.u[3] = c3;
                B1.u[0] = q2; B1.u[1] = q3; B1.u[2] = c6; B1.u[3] = c7;
            }
            o0 = __builtin_amdgcn_mfma_f32_32x32x16_bf16(gA0, B0.v, o0, 0, 0, 0);
            o1 = __builtin_amdgcn_mfma_f32_32x32x16_bf16(gA1, B0.v, o1, 0, 0, 0);
            o0 = __builtin_amdgcn_mfma_f32_32x32x16_bf16(gB0, B1.v, o0, 0, 0, 0);
            o1 = __builtin_amdgcn_mfma_f32_32x32x16_bf16(gB1, B1.v, o1, 0, 0, 0);
        }
        if (grp < 7) {  // write staged group late (loads have drained by now)
#pragma unroll
            for (int i = 0; i < 5; ++i) sbuf[cur ^ 1][(tid >> 6) + 4 * i][lane] = stg[i];
        }
        __syncthreads();
    }

    float sm = sm0 + sm1;
    sm += __shfl_xor(sm, 32);        // combine complementary m-halves
    const float inv = 1.f / sm;
#pragma unroll
    for (int jj = 0; jj < 16; ++jj) { o0[jj] *= inv; o1[jj] *= inv; }

    // Build out-proj B-frags from o^T frags: slot j of chunk kc holds ci=16kc+8h+j.
    bf16x8 Bf[4];
#pragma unroll
    for (int kc = 0; kc < 4; ++kc) {
        const f32x16& oo = (kc < 2) ? o0 : o1;
        const int base = 8 * (kc & 1);
        uint Pa0 = pk2(oo[base + 0], oo[base + 1]);
        uint Pa1 = pk2(oo[base + 2], oo[base + 3]);
        uint Pb0 = pk2(oo[base + 4], oo[base + 5]);
        uint Pb1 = pk2(oo[base + 6], oo[base + 7]);
        uint z0 = h ? Pa0 : Pb0, z1 = h ? Pa1 : Pb1;  // send what partner needs
        uint r0 = (uint)__shfl_xor((int)z0, 32);
        uint r1 = (uint)__shfl_xor((int)z1, 32);
        union { bf16x8 v; uint u[4]; } Bx;
        if (h == 0) { Bx.u[0] = Pa0; Bx.u[1] = Pa1; Bx.u[2] = r0;  Bx.u[3] = r1; }
        else        { Bx.u[0] = r0;  Bx.u[1] = r1;  Bx.u[2] = Pb0; Bx.u[3] = Pb1; }
        Bf[kc] = Bx.v;
    }

    const float gm = gamma[0];
#pragma unroll
    for (int cof = 0; cof < 4; ++cof) {
        f32x16 oc = {0,0,0,0,0,0,0,0,0,0,0,0,0,0,0,0};
#pragma unroll
        for (int kc = 0; kc < 4; ++kc) {
            const float* wp = w_o + (32 * cof + l31) * 64 + 16 * kc + 8 * h;
            float4 wa = *(const float4*)(wp);
            float4 wb = *(const float4*)(wp + 4);
            union { bf16x8 v; uint u[4]; } W;
            W.u[0] = pk2(wa.x, wa.y); W.u[1] = pk2(wa.z, wa.w);
            W.u[2] = pk2(wb.x, wb.y); W.u[3] = pk2(wb.z, wb.w);
            oc = __builtin_amdgcn_mfma_f32_32x32x16_bf16(W.v, Bf[kc], oc, 0, 0, 0);
        }
#pragma unroll
        for (int jj = 0; jj < 16; ++jj) {
            int co = 32 * cof + (jj & 3) + 8 * (jj >> 2) + 4 * h;
            size_t idx = ((size_t)(b * 128 + co)) * 4096 + n;
            out[idx] = fmaf(gm, oc[jj], x[idx]);
        }
    }
}

extern "C" void kernel_launch(void* const* d_in, const int* in_sizes, int n_in,
                              void* d_out, int out_size, void* d_ws, size_t ws_size,
                              hipStream_t stream) {
    const float* x       = (const float*)d_in[0];
    const float* w_theta = (const float*)d_in[1];
    const float* w_phi   = (const float*)d_in[2];
    const float* w_g     = (const float*)d_in[3];
    const float* w_o     = (const float*)d_in[4];
    const float* gamma   = (const float*)d_in[5];
    float* out = (float*)d_out;

    ushort* theta_b = (ushort*)d_ws;
    ushort* phi_b   = theta_b + 1048576;
    ushort* g_b     = phi_b + 262144;

    k_convs<<<512, 256, 0, stream>>>(x, w_theta, w_phi, w_g, theta_b, phi_b, g_b);
    k_attn<<<512, 256, 0, stream>>>(theta_b, phi_b, g_b, w_o, x, gamma, out);
}